// Round 1
// baseline (27482.544 us; speedup 1.0000x reference)
//
#include <hip/hip_runtime.h>
#include <hip/hip_bf16.h>
#include <cstddef>

// Problem constants
#define kT    256
#define kB    128
#define kINP  512
#define kH    512
#define kK    32     // LAST_K short-term slots
#define kR    64     // RSIZE long-term slots
#define kNEG  (-1e30f)

// ---------------------------------------------------------------------------
// init: build Wcat = [Vw | Vaw] (512 x 1024), zero long_scores/buck/fcnt,
// set long_idx = -1
// ---------------------------------------------------------------------------
__global__ __launch_bounds__(256) void init_k(
    const float* __restrict__ Vw, const float* __restrict__ Vaw,
    float* __restrict__ Wcat, float* __restrict__ lsc, float* __restrict__ bck,
    int* __restrict__ lidx, int* __restrict__ fct)
{
    int i = blockIdx.x * 256 + threadIdx.x;
    if (i < 512 * 1024) {
        int k = i >> 10, n = i & 1023;
        Wcat[i] = (n < 512) ? Vw[k * 512 + n] : Vaw[k * 512 + (n - 512)];
    }
    if (i < kT * kB) lsc[i] = 0.0f;
    if (i < kB * kR) bck[i] = 0.0f;
    if (i < kR * kB) lidx[i] = -1;
    if (i < kB)      fct[i] = 0;
}

// ---------------------------------------------------------------------------
// t = 0: st = pre = XU[0]; hs[0] = tanh(pre)
// ---------------------------------------------------------------------------
__global__ __launch_bounds__(256) void step0_k(
    const float* __restrict__ XU, float* __restrict__ hs, float* __restrict__ st)
{
    int i = blockIdx.x * 256 + threadIdx.x;
    if (i < kB * kH) {
        float p = XU[i];
        st[i] = p;
        hs[i] = tanhf(p);
    }
}

// ---------------------------------------------------------------------------
// Generic fp32 tiled GEMM.  C[M,N] = A[M,K] @ W[K,N]
// MODE 0: C = A@W (+bias[n] if bias)                     (XU, HSU, va)
// MODE 1: W is Wcat (N=1024).  For n<512:  hs = tanh(Dadd + acc)  -> C
//                              For n>=512: va = acc               -> C2
// Tiles: BM=32, BN=64, BK=32, 256 threads, 8 acc/thread.
// ---------------------------------------------------------------------------
template <int MODE>
__global__ __launch_bounds__(256) void gemm_k(
    const float* __restrict__ A, const float* __restrict__ W,
    const float* __restrict__ bias, const float* __restrict__ Dadd,
    float* __restrict__ C, float* __restrict__ C2,
    int M, int N, int K)
{
    __shared__ float As[32][36];
    __shared__ float Ws[32][68];
    const int tid = threadIdx.x;
    const int n0 = blockIdx.x * 64;
    const int m0 = blockIdx.y * 32;
    const int ty = tid >> 4, tx = tid & 15;
    const int arow = tid >> 3, ac4 = (tid & 7) << 2;
    const int wrow = tid >> 4, wc4 = (tid & 15) << 2;

    float acc[2][4] = {};

    for (int k0 = 0; k0 < K; k0 += 32) {
        float4 av = *reinterpret_cast<const float4*>(&A[(size_t)(m0 + arow) * K + k0 + ac4]);
        float4 w0 = *reinterpret_cast<const float4*>(&W[(size_t)(k0 + wrow) * N + n0 + wc4]);
        float4 w1 = *reinterpret_cast<const float4*>(&W[(size_t)(k0 + wrow + 16) * N + n0 + wc4]);
        *reinterpret_cast<float4*>(&As[arow][ac4]) = av;
        *reinterpret_cast<float4*>(&Ws[wrow][wc4]) = w0;
        *reinterpret_cast<float4*>(&Ws[wrow + 16][wc4]) = w1;
        __syncthreads();
#pragma unroll
        for (int kk = 0; kk < 32; ++kk) {
            float a0 = As[ty * 2 + 0][kk];
            float a1 = As[ty * 2 + 1][kk];
            float4 wv = *reinterpret_cast<float4*>(&Ws[kk][tx * 4]);
            acc[0][0] += a0 * wv.x; acc[0][1] += a0 * wv.y;
            acc[0][2] += a0 * wv.z; acc[0][3] += a0 * wv.w;
            acc[1][0] += a1 * wv.x; acc[1][1] += a1 * wv.y;
            acc[1][2] += a1 * wv.z; acc[1][3] += a1 * wv.w;
        }
        __syncthreads();
    }

#pragma unroll
    for (int r = 0; r < 2; ++r) {
        int m = m0 + ty * 2 + r;
#pragma unroll
        for (int j = 0; j < 4; ++j) {
            int n = n0 + tx * 4 + j;
            float val = acc[r][j];
            if (MODE == 0) {
                if (bias) val += bias[n];
                C[(size_t)m * N + n] = val;
            } else {
                if (n < 512) {
                    C[(size_t)m * 512 + n] = tanhf(Dadd[(size_t)m * 512 + n] + val);
                } else {
                    C2[(size_t)m * 512 + (n - 512)] = val;
                }
            }
        }
    }
}

// ---------------------------------------------------------------------------
// fast tanh for the attention scores (error ~1e-7, stable at +-inf)
// ---------------------------------------------------------------------------
__device__ __forceinline__ float ftanh(float x)
{
    float e = __expf(2.0f * x);
    return 1.0f - 2.0f * __builtin_amdgcn_rcpf(e + 1.0f);
}

// ---------------------------------------------------------------------------
// Attention step t (t >= 1).  One block per batch element b.
//  es[m] = v . tanh(va[b] + HSU[row_m][b])   (row_m < 0 -> -1e30)
//  alpha = softmax(es); ct = sum alpha * hs[row_m][b]
//  st_new = 0.5*(hs[t-1][b] + ct)  -> st
//  long_scores[row_k][b] += alpha[k]  (k < 32, valid)
//  eviction bookkeeping (per reference semantics)
// ---------------------------------------------------------------------------
__global__ __launch_bounds__(256) void attn_k(
    const float* __restrict__ hs, const float* __restrict__ HSU,
    const float* __restrict__ va, const float* __restrict__ vvec,
    float* __restrict__ st, float* __restrict__ lsc,
    float* __restrict__ bck, int* __restrict__ lidx, int* __restrict__ fct,
    int t)
{
    const int b = blockIdx.x;
    const int tid = threadIdx.x;
    __shared__ float va_sh[512];
    __shared__ float v_sh[512];
    __shared__ int   rowm[96];
    __shared__ float es[96];
    __shared__ float alpha[96];

    for (int i = tid; i < 512; i += 256) {
        va_sh[i] = va[b * 512 + i];
        v_sh[i] = vvec[i];
    }
    if (tid < 96) {
        int row;
        if (tid < 32) {
            int md = (t - 1 - tid) % 32;
            if (md < 0) md += 32;
            int tau = t - 1 - md;
            row = (tau >= 0) ? tau : -1;
        } else {
            row = lidx[(tid - 32) * kB + b];
        }
        rowm[tid] = row;
    }
    __syncthreads();

    // es: 4 waves x 24 slots, 64-lane dot over H=512
    const int wave = tid >> 6, lane = tid & 63;
#pragma unroll
    for (int mi = 0; mi < 24; ++mi) {
        int m = wave * 24 + mi;
        int row = rowm[m];
        float part = 0.0f;
        if (row >= 0) {
            const float* up = HSU + ((size_t)row * kB + b) * 512;
#pragma unroll
            for (int j = 0; j < 8; ++j) {
                int h = j * 64 + lane;
                part += v_sh[h] * ftanh(va_sh[h] + up[h]);
            }
        }
#pragma unroll
        for (int off = 32; off > 0; off >>= 1) part += __shfl_down(part, off);
        if (lane == 0) es[m] = (row >= 0) ? part : kNEG;
    }
    __syncthreads();

    // softmax over 96 (serial on thread 0; tiny)
    if (tid == 0) {
        float mx = es[0];
        for (int m = 1; m < 96; ++m) mx = fmaxf(mx, es[m]);
        float s = 0.0f;
        for (int m = 0; m < 96; ++m) { float e = __expf(es[m] - mx); alpha[m] = e; s += e; }
        float inv = 1.0f / s;
        for (int m = 0; m < 96; ++m) alpha[m] *= inv;
    }
    __syncthreads();

    // ct and st_new
    for (int h = tid; h < 512; h += 256) {
        float ct = 0.0f;
#pragma unroll 4
        for (int m = 0; m < 96; ++m) {
            int row = rowm[m];
            if (row >= 0) ct += alpha[m] * hs[((size_t)row * kB + b) * 512 + h];
        }
        float lasth = hs[((size_t)(t - 1) * kB + b) * 512 + h];
        st[b * 512 + h] = 0.5f * (lasth + ct);
    }

    // accumulate attention mass per timestep (short-term slots only)
    if (tid < 32) {
        int row = rowm[tid];
        if (row >= 0) lsc[(size_t)row * kB + b] += alpha[tid];
    }
    __syncthreads();

    // conditional bucket eviction (reads the just-updated long_scores)
    if (tid == 0 && t >= kK) {
        float score_t = lsc[(size_t)(t - kK) * kB + b];
        int fc = fct[b];
        bool not_full = fc < kR;
        float mn = bck[b * kR + 0];
        int mp = 0;
        for (int r = 1; r < kR; ++r) {
            float bv = bck[b * kR + r];
            if (bv < mn) { mn = bv; mp = r; }
        }
        bool rep = score_t > mn;
        bool doev = not_full || rep;
        int pos = not_full ? fc : mp;
        if (doev) {
            lidx[pos * kB + b] = t - kK;
            bck[b * kR + pos] = score_t;
            if (not_full) fct[b] = fc + 1;
        }
    }
}

// ---------------------------------------------------------------------------
extern "C" void kernel_launch(void* const* d_in, const int* in_sizes, int n_in,
                              void* d_out, int out_size, void* d_ws, size_t ws_size,
                              hipStream_t stream)
{
    const float* x   = (const float*)d_in[0];
    const float* Uw  = (const float*)d_in[1];
    const float* Ub  = (const float*)d_in[2];
    const float* Vw  = (const float*)d_in[3];
    const float* Uaw = (const float*)d_in[4];
    const float* Vaw = (const float*)d_in[5];
    const float* vv  = (const float*)d_in[6];
    float* hs = (float*)d_out;

    float* ws = (float*)d_ws;
    const size_t TBH = (size_t)kT * kB * kH;
    float* XU   = ws;                      // T*B*H
    float* HSU  = XU + TBH;                // T*B*H
    float* stb  = HSU + TBH;               // B*H
    float* vab  = stb + (size_t)kB * kH;   // B*H
    float* lsc  = vab + (size_t)kB * kH;   // T*B
    float* bck  = lsc + (size_t)kT * kB;   // B*R
    float* Wcat = bck + (size_t)kB * kR;   // 512*1024
    int*   lidx = (int*)(Wcat + 512 * 1024); // R*B
    int*   fct  = lidx + kR * kB;            // B

    init_k<<<2048, 256, 0, stream>>>(Vw, Vaw, Wcat, lsc, bck, lidx, fct);

    // XU = x @ Uw + Ub   (M = T*B = 32768)
    gemm_k<0><<<dim3(kH / 64, (kT * kB) / 32), 256, 0, stream>>>(
        x, Uw, Ub, nullptr, XU, nullptr, kT * kB, kH, kINP);

    // t = 0
    step0_k<<<(kB * kH) / 256, 256, 0, stream>>>(XU, hs, stb);
    gemm_k<0><<<dim3(8, 4), 256, 0, stream>>>(hs, Uaw, nullptr, nullptr, HSU, nullptr, kB, kH, kH);
    gemm_k<0><<<dim3(8, 4), 256, 0, stream>>>(stb, Vaw, nullptr, nullptr, vab, nullptr, kB, kH, kH);

    for (int t = 1; t < kT; ++t) {
        attn_k<<<kB, 256, 0, stream>>>(hs, HSU, vab, vv, stb, lsc, bck, lidx, fct, t);
        // [h-pre | va_next] = st @ [Vw | Vaw];  hs[t] = tanh(XU[t] + h-pre)
        gemm_k<1><<<dim3(16, 4), 256, 0, stream>>>(
            stb, Wcat, nullptr, XU + (size_t)t * kB * kH,
            hs + (size_t)t * kB * kH, vab, kB, 1024, kH);
        // HSU[t] = hs[t] @ Uaw
        gemm_k<0><<<dim3(8, 4), 256, 0, stream>>>(
            hs + (size_t)t * kB * kH, Uaw, nullptr, nullptr,
            HSU + (size_t)t * kB * kH, nullptr, kB, kH, kH);
    }
}

// Round 2
// 16808.228 us; speedup vs baseline: 1.6351x; 1.6351x over previous
//
#include <hip/hip_runtime.h>
#include <hip/hip_bf16.h>
#include <cstddef>

#define kT 256
#define kB 128
#define kINP 512
#define kH 512
#define kK 32
#define kR 64
#define kNEG (-1e30f)

// ---------------------------------------------------------------------------
// XU = x @ Uw + Ub   (M = T*B = 32768, N = K = 512), fp32 LDS-tiled GEMM
// ---------------------------------------------------------------------------
__global__ __launch_bounds__(256) void gemm_xu(
    const float* __restrict__ A, const float* __restrict__ W,
    const float* __restrict__ bias, float* __restrict__ C,
    int M, int N, int K)
{
    __shared__ float As[32][36];
    __shared__ float Ws[32][68];
    const int tid = threadIdx.x;
    const int n0 = blockIdx.x * 64;
    const int m0 = blockIdx.y * 32;
    const int ty = tid >> 4, tx = tid & 15;
    const int arow = tid >> 3, ac4 = (tid & 7) << 2;
    const int wrow = tid >> 4, wc4 = (tid & 15) << 2;

    float acc[2][4] = {};

    for (int k0 = 0; k0 < K; k0 += 32) {
        float4 av = *reinterpret_cast<const float4*>(&A[(size_t)(m0 + arow) * K + k0 + ac4]);
        float4 w0 = *reinterpret_cast<const float4*>(&W[(size_t)(k0 + wrow) * N + n0 + wc4]);
        float4 w1 = *reinterpret_cast<const float4*>(&W[(size_t)(k0 + wrow + 16) * N + n0 + wc4]);
        *reinterpret_cast<float4*>(&As[arow][ac4]) = av;
        *reinterpret_cast<float4*>(&Ws[wrow][wc4]) = w0;
        *reinterpret_cast<float4*>(&Ws[wrow + 16][wc4]) = w1;
        __syncthreads();
#pragma unroll
        for (int kk = 0; kk < 32; ++kk) {
            float a0 = As[ty * 2 + 0][kk];
            float a1 = As[ty * 2 + 1][kk];
            float4 wv = *reinterpret_cast<float4*>(&Ws[kk][tx * 4]);
            acc[0][0] += a0 * wv.x; acc[0][1] += a0 * wv.y;
            acc[0][2] += a0 * wv.z; acc[0][3] += a0 * wv.w;
            acc[1][0] += a1 * wv.x; acc[1][1] += a1 * wv.y;
            acc[1][2] += a1 * wv.z; acc[1][3] += a1 * wv.w;
        }
        __syncthreads();
    }

#pragma unroll
    for (int r = 0; r < 2; ++r) {
        int m = m0 + ty * 2 + r;
#pragma unroll
        for (int j = 0; j < 4; ++j) {
            int n = n0 + tx * 4 + j;
            C[(size_t)m * N + n] = acc[r][j] + bias[n];
        }
    }
}

// fast tanh for attention scores (error ~1e-7, stable at +-inf)
__device__ __forceinline__ float ftanh(float x)
{
    float e = __expf(2.0f * x);
    return 1.0f - 2.0f * __builtin_amdgcn_rcpf(e + 1.0f);
}

// ---------------------------------------------------------------------------
// Persistent recurrence kernel: one block per batch element b, 512 threads.
// Runs all 255 steps; all cross-step state in LDS, HSU/hs caches in global.
// ---------------------------------------------------------------------------
__global__ __launch_bounds__(512) void rnn_persist(
    const float* __restrict__ Vw, const float* __restrict__ Vaw,
    const float* __restrict__ Uaw, const float* __restrict__ vvec,
    const float* __restrict__ XU, float* __restrict__ HSU,
    float* __restrict__ hs)
{
    const int b = blockIdx.x;
    const int tid = threadIdx.x;
    const int q = tid >> 7;            // 0..3 (128-thread group)
    const int i4 = (tid & 127) << 2;   // float4 column base 0..508
    const int wv = tid >> 6, lane = tid & 63;

    __shared__ float st_sh[512], h_sh[512], va_sh[512], v_sh[512];
    __shared__ float part[2048];
    __shared__ float lsc_sh[kT];
    __shared__ float es_sh[96], w_sh[96];
    __shared__ int   rowm[96];
    __shared__ float buck_sh[kR];
    __shared__ int   lidx_sh[kR];
    __shared__ int   fcnt_sh;
    __shared__ float red0, red1;

    // ---- prologue (t = 0): st = XU[0][b] (pre), h0 = tanh(pre)
    {
        float stv = XU[(size_t)b * kH + tid];
        st_sh[tid] = stv;
        float h0 = tanhf(stv);
        h_sh[tid] = h0;
        hs[(size_t)b * kH + tid] = h0;
        v_sh[tid] = vvec[tid];
        if (tid < kT) lsc_sh[tid] = 0.0f;
        if (tid < kR) { buck_sh[tid] = 0.0f; lidx_sh[tid] = -1; }
        if (tid == 0) fcnt_sh = 0;
    }
    __syncthreads();

    // ---- va = st_0 @ Vaw  (4-way k-split, float4 columns)
    {
        float4 acc = {0, 0, 0, 0};
#pragma unroll 4
        for (int k = 0; k < kH; k += 4) {
            float s = st_sh[k + q];
            float4 w = *reinterpret_cast<const float4*>(&Vaw[(size_t)(k + q) * kH + i4]);
            acc.x += s * w.x; acc.y += s * w.y; acc.z += s * w.z; acc.w += s * w.w;
        }
        *reinterpret_cast<float4*>(&part[q * 512 + i4]) = acc;
        __syncthreads();
        va_sh[tid] = part[tid] + part[512 + tid] + part[1024 + tid] + part[1536 + tid];
        __syncthreads();
    }

    for (int t = 1; t < kT; ++t) {
        // ---- matvec A: u = h_{t-1} @ Uaw -> HSU[t-1][b]
        {
            float4 acc = {0, 0, 0, 0};
#pragma unroll 4
            for (int k = 0; k < kH; k += 4) {
                float s = h_sh[k + q];
                float4 w = *reinterpret_cast<const float4*>(&Uaw[(size_t)(k + q) * kH + i4]);
                acc.x += s * w.x; acc.y += s * w.y; acc.z += s * w.z; acc.w += s * w.w;
            }
            *reinterpret_cast<float4*>(&part[q * 512 + i4]) = acc;
            __syncthreads();
            float u = part[tid] + part[512 + tid] + part[1024 + tid] + part[1536 + tid];
            HSU[((size_t)(t - 1) * kB + b) * kH + tid] = u;
        }
        if (tid < 96) {
            int row;
            if (tid < 32) { int md = (t + 31 - tid) & 31; row = t - 1 - md; if (row < 0) row = -1; }
            else row = lidx_sh[tid - 32];
            rowm[tid] = row;
        }
        __syncthreads();  // HSU[t-1] write drained; rowm ready

        // ---- es[m] = v . tanh(va + HSU[row][b]), 8 waves x 12 rows
#pragma unroll
        for (int r = 0; r < 12; ++r) {
            int m = wv * 12 + r;
            int row = rowm[m];
            float p = 0.0f;
            if (row >= 0) {
                const float* up = &HSU[((size_t)row * kB + b) * kH];
#pragma unroll
                for (int j = 0; j < 8; ++j) {
                    int hh = j * 64 + lane;
                    p += v_sh[hh] * ftanh(va_sh[hh] + up[hh]);
                }
            }
#pragma unroll
            for (int off = 32; off; off >>= 1) p += __shfl_down(p, off);
            if (lane == 0) es_sh[m] = (row >= 0) ? p : kNEG;
        }
        __syncthreads();

        // ---- softmax (unnormalized weights + 1/sum)
        if (tid < 64) {
            float a = es_sh[tid];
            float c = (tid < 32) ? es_sh[64 + tid] : kNEG;
            float mx = fmaxf(a, c);
#pragma unroll
            for (int off = 32; off; off >>= 1) mx = fmaxf(mx, __shfl_xor(mx, off));
            if (tid == 0) red0 = mx;
        }
        __syncthreads();
        if (tid < 96) w_sh[tid] = __expf(es_sh[tid] - red0);
        __syncthreads();
        if (tid < 64) {
            float a = w_sh[tid] + ((tid < 32) ? w_sh[64 + tid] : 0.0f);
#pragma unroll
            for (int off = 32; off; off >>= 1) a += __shfl_xor(a, off);
            if (tid == 0) red1 = 1.0f / a;
        }
        __syncthreads();

        // ---- ct & st_new
        {
            float ct = 0.0f;
#pragma unroll 4
            for (int m = 0; m < 96; ++m) {
                int row = rowm[m];
                if (row >= 0) ct += w_sh[m] * hs[((size_t)row * kB + b) * kH + tid];
            }
            st_sh[tid] = 0.5f * (h_sh[tid] + ct * red1);
        }
        __syncthreads();

        // ---- long_scores accumulation, then eviction (reference order)
        if (tid < 32) {
            int row = rowm[tid];
            if (row >= 0) lsc_sh[row] += w_sh[tid] * red1;
        }
        __syncthreads();
        if (tid == 0 && t >= kK) {
            float score = lsc_sh[t - kK];
            int fc = fcnt_sh;
            bool nf = fc < kR;
            float mn = buck_sh[0]; int mp = 0;
            for (int r = 1; r < kR; ++r) {
                float bv = buck_sh[r];
                if (bv < mn) { mn = bv; mp = r; }
            }
            if (nf || score > mn) {
                int pos = nf ? fc : mp;
                lidx_sh[pos] = t - kK;
                buck_sh[pos] = score;
                if (nf) fcnt_sh = fc + 1;
            }
        }

        // ---- matvec B: [h-pre | va'] = st @ [Vw | Vaw]  (2 mats x 2 k-parities)
        {
            const float* M = (q & 1) ? Vaw : Vw;
            const int ko = q >> 1;
            float4 acc = {0, 0, 0, 0};
#pragma unroll 4
            for (int k = 0; k < kH; k += 2) {
                float s = st_sh[k + ko];
                float4 w = *reinterpret_cast<const float4*>(&M[(size_t)(k + ko) * kH + i4]);
                acc.x += s * w.x; acc.y += s * w.y; acc.z += s * w.z; acc.w += s * w.w;
            }
            *reinterpret_cast<float4*>(&part[(q >> 1) * 1024 + (q & 1) * 512 + i4]) = acc;
            __syncthreads();
            float preh = part[tid] + part[1024 + tid] + XU[((size_t)t * kB + b) * kH + tid];
            float hv = tanhf(preh);
            float vav = part[512 + tid] + part[1536 + tid];
            h_sh[tid] = hv;
            va_sh[tid] = vav;
            hs[((size_t)t * kB + b) * kH + tid] = hv;
        }
        __syncthreads();
    }
}

// ---------------------------------------------------------------------------
extern "C" void kernel_launch(void* const* d_in, const int* in_sizes, int n_in,
                              void* d_out, int out_size, void* d_ws, size_t ws_size,
                              hipStream_t stream)
{
    const float* x   = (const float*)d_in[0];
    const float* Uw  = (const float*)d_in[1];
    const float* Ub  = (const float*)d_in[2];
    const float* Vw  = (const float*)d_in[3];
    const float* Uaw = (const float*)d_in[4];
    const float* Vaw = (const float*)d_in[5];
    const float* vv  = (const float*)d_in[6];
    float* hs = (float*)d_out;

    float* ws = (float*)d_ws;
    const size_t TBH = (size_t)kT * kB * kH;
    float* XU  = ws;         // T*B*H
    float* HSU = ws + TBH;   // T*B*H

    // XU = x @ Uw + Ub
    gemm_xu<<<dim3(kH / 64, (kT * kB) / 32), 256, 0, stream>>>(
        x, Uw, Ub, XU, kT * kB, kH, kINP);

    // whole recurrence: one block per batch element
    rnn_persist<<<kB, 512, 0, stream>>>(Vw, Vaw, Uaw, vv, XU, HSU, hs);
}

// Round 3
// 13687.213 us; speedup vs baseline: 2.0079x; 1.2280x over previous
//
#include <hip/hip_runtime.h>
#include <hip/hip_bf16.h>
#include <cstddef>

#define kT 256
#define kB 128
#define kINP 512
#define kH 512
#define kK 32
#define kR 64
#define kNEG (-1e30f)

// ---------------------------------------------------------------------------
// agent-scope (device-coherent, cache-bypassing) accessors for data exchanged
// between the two blocks of a pair (they may sit on different XCDs).
// ---------------------------------------------------------------------------
__device__ __forceinline__ void ag_store(float* p, float v) {
    __hip_atomic_store(p, v, __ATOMIC_RELAXED, __HIP_MEMORY_SCOPE_AGENT);
}
__device__ __forceinline__ float ag_load(const float* p) {
    return __hip_atomic_load(p, __ATOMIC_RELAXED, __HIP_MEMORY_SCOPE_AGENT);
}

// fast tanh for attention scores (error ~1e-7, stable at +-inf)
__device__ __forceinline__ float ftanh(float x)
{
    float e = __expf(2.0f * x);
    return 1.0f - 2.0f * __builtin_amdgcn_rcpf(e + 1.0f);
}

// ---------------------------------------------------------------------------
// XU = x @ Uw + Ub   (M = T*B = 32768, N = K = 512), fp32 LDS-tiled GEMM
// ---------------------------------------------------------------------------
__global__ __launch_bounds__(256) void gemm_xu(
    const float* __restrict__ A, const float* __restrict__ W,
    const float* __restrict__ bias, float* __restrict__ C,
    int M, int N, int K)
{
    __shared__ float As[32][36];
    __shared__ float Ws[32][68];
    const int tid = threadIdx.x;
    const int n0 = blockIdx.x * 64;
    const int m0 = blockIdx.y * 32;
    const int ty = tid >> 4, tx = tid & 15;
    const int arow = tid >> 3, ac4 = (tid & 7) << 2;
    const int wrow = tid >> 4, wc4 = (tid & 15) << 2;

    float acc[2][4] = {};

    for (int k0 = 0; k0 < K; k0 += 32) {
        float4 av = *reinterpret_cast<const float4*>(&A[(size_t)(m0 + arow) * K + k0 + ac4]);
        float4 w0 = *reinterpret_cast<const float4*>(&W[(size_t)(k0 + wrow) * N + n0 + wc4]);
        float4 w1 = *reinterpret_cast<const float4*>(&W[(size_t)(k0 + wrow + 16) * N + n0 + wc4]);
        *reinterpret_cast<float4*>(&As[arow][ac4]) = av;
        *reinterpret_cast<float4*>(&Ws[wrow][wc4]) = w0;
        *reinterpret_cast<float4*>(&Ws[wrow + 16][wc4]) = w1;
        __syncthreads();
#pragma unroll
        for (int kk = 0; kk < 32; ++kk) {
            float a0 = As[ty * 2 + 0][kk];
            float a1 = As[ty * 2 + 1][kk];
            float4 wv = *reinterpret_cast<float4*>(&Ws[kk][tx * 4]);
            acc[0][0] += a0 * wv.x; acc[0][1] += a0 * wv.y;
            acc[0][2] += a0 * wv.z; acc[0][3] += a0 * wv.w;
            acc[1][0] += a1 * wv.x; acc[1][1] += a1 * wv.y;
            acc[1][2] += a1 * wv.z; acc[1][3] += a1 * wv.w;
        }
        __syncthreads();
    }

#pragma unroll
    for (int r = 0; r < 2; ++r) {
        int m = m0 + ty * 2 + r;
#pragma unroll
        for (int j = 0; j < 4; ++j) {
            int n = n0 + tx * 4 + j;
            C[(size_t)m * N + n] = acc[r][j] + bias[n];
        }
    }
}

__global__ __launch_bounds__(256) void init_flags_k(int* __restrict__ flags)
{
    int i = blockIdx.x * 256 + threadIdx.x;
    if (i < kB * 3 * 2) flags[i] = 0;
}

// ---------------------------------------------------------------------------
// Pair-split persistent recurrence: blockIdx = 2*b + half.
// Each block owns columns C = [half*256, half*256+256) of every matvec and a
// redundant copy of the per-b scalar state (softmax, scores, eviction).
// ---------------------------------------------------------------------------
__global__ __launch_bounds__(512) void rnn_pair(
    const float* __restrict__ Vw, const float* __restrict__ Vaw,
    const float* __restrict__ Uaw, const float* __restrict__ vvec,
    const float* __restrict__ XU, float* __restrict__ HSU,
    float* __restrict__ hs, float* __restrict__ esx,
    float* __restrict__ stx, int* __restrict__ flags)
{
    const int bid = blockIdx.x;
    const int b = bid >> 1, half = bid & 1;
    const int C0 = half << 8;            // column base of this block's half
    const int tid = threadIdx.x;
    const int kq = tid >> 6;             // 0..7  (k-parity / wave id)
    const int c4 = (tid & 63) << 2;      // float4 col offset within half
    const int lane = tid & 63;

    __shared__ __align__(16) float h_sh[512];     // full h_{t-1}
    __shared__ __align__(16) float st_sh[512];    // full st
    __shared__ __align__(16) float va_sh[256];    // own cols of va
    __shared__ __align__(16) float u_sh[256];     // own cols of HSU[t-1]
    __shared__ __align__(16) float sthalf[256];   // own cols of st
    __shared__ __align__(16) float v_sh[256];     // own cols of v
    __shared__ __align__(16) float part[8][260];
    __shared__ __align__(16) float part2[8][260];
    __shared__ float es_own[96], es_sh[96], w_sh[96];
    __shared__ int   rowm[96];
    __shared__ float lsc_sh[kT];
    __shared__ float buck_sh[kR];
    __shared__ int   lidx_sh[kR];
    __shared__ int   fcnt_sh;
    __shared__ float red0, red1;

    int* fC_own = &flags[(b * 3 + 0) * 2 + half];
    int* fB_own = &flags[(b * 3 + 1) * 2 + half];
    int* fS_own = &flags[(b * 3 + 2) * 2 + half];
    int* fC_par = &flags[(b * 3 + 0) * 2 + (half ^ 1)];
    int* fB_par = &flags[(b * 3 + 1) * 2 + (half ^ 1)];
    int* fS_par = &flags[(b * 3 + 2) * 2 + (half ^ 1)];

    auto wait_ge = [&](int* f, int target) {
        if (tid == 0) {
            while (__hip_atomic_load(f, __ATOMIC_ACQUIRE, __HIP_MEMORY_SCOPE_AGENT) < target)
                __builtin_amdgcn_s_sleep(1);
        }
        __syncthreads();
    };
    auto set_flag = [&](int* f, int val) {
        __syncthreads();   // all data stores issued + drained (vmcnt) per wave
        if (tid == 0)
            __hip_atomic_store(f, val, __ATOMIC_RELEASE, __HIP_MEMORY_SCOPE_AGENT);
    };

    // ---- prologue (t = 0)
    if (tid < 256) {
        v_sh[tid] = vvec[C0 + tid];
        lsc_sh[tid] = 0.0f;
    }
    if (tid < kR) { buck_sh[tid] = 0.0f; lidx_sh[tid] = -1; }
    if (tid == 0) fcnt_sh = 0;
    st_sh[tid] = XU[(size_t)b * kH + tid];   // st_0 = pre (full row, input)
    __syncthreads();
    if (tid < 256) {
        float h0 = tanhf(st_sh[C0 + tid]);
        ag_store(&hs[(size_t)b * kH + C0 + tid], h0);
    }
    set_flag(fC_own, 1);
    // va_0 = st_0 @ Vaw[:, C]
    {
        float4 acc = {0, 0, 0, 0};
#pragma unroll 8
        for (int k = 0; k < kH; k += 8) {
            float s = st_sh[k + kq];
            const float4 w = *reinterpret_cast<const float4*>(&Vaw[(size_t)(k + kq) * kH + C0 + c4]);
            acc.x += s * w.x; acc.y += s * w.y; acc.z += s * w.z; acc.w += s * w.w;
        }
        *reinterpret_cast<float4*>(&part[kq][c4]) = acc;
        __syncthreads();
        if (tid < 256) {
            float s = 0.0f;
#pragma unroll
            for (int j = 0; j < 8; ++j) s += part[j][tid];
            va_sh[tid] = s;
        }
        __syncthreads();
    }

    for (int t = 1; t < kT; ++t) {
        // ---- assemble full h_{t-1} (partner half guarded by fC)
        wait_ge(fC_par, t);
        h_sh[tid] = ag_load(&hs[((size_t)(t - 1) * kB + b) * kH + tid]);
        __syncthreads();

        // ---- matvec A: u[C] = h_{t-1} @ Uaw[:, C]
        {
            float4 acc = {0, 0, 0, 0};
#pragma unroll 8
            for (int k = 0; k < kH; k += 8) {
                float s = h_sh[k + kq];
                const float4 w = *reinterpret_cast<const float4*>(&Uaw[(size_t)(k + kq) * kH + C0 + c4]);
                acc.x += s * w.x; acc.y += s * w.y; acc.z += s * w.z; acc.w += s * w.w;
            }
            *reinterpret_cast<float4*>(&part[kq][c4]) = acc;
        }
        if (tid < 96) {
            int row;
            if (tid < kK) { int md = (t + 31 - tid) & 31; row = t - 1 - md; }
            else row = lidx_sh[tid - kK];
            rowm[tid] = row;
        }
        __syncthreads();
        if (tid < 256) {
            float u = 0.0f;
#pragma unroll
            for (int j = 0; j < 8; ++j) u += part[j][tid];
            u_sh[tid] = u;
            HSU[((size_t)(t - 1) * kB + b) * kH + C0 + tid] = u;  // block-private
        }
        __syncthreads();

        // ---- es column-partials over own 256 cols (96 rows, 12/wave)
#pragma unroll
        for (int r = 0; r < 12; ++r) {
            int m = kq * 12 + r;
            int row = rowm[m];
            float p = 0.0f;
            if (row >= 0) {
                float4 uu;
                if (row == t - 1) uu = *reinterpret_cast<const float4*>(&u_sh[lane * 4]);
                else uu = *reinterpret_cast<const float4*>(&HSU[((size_t)row * kB + b) * kH + C0 + lane * 4]);
                const float4 vav = *reinterpret_cast<const float4*>(&va_sh[lane * 4]);
                const float4 vvv = *reinterpret_cast<const float4*>(&v_sh[lane * 4]);
                p = vvv.x * ftanh(vav.x + uu.x) + vvv.y * ftanh(vav.y + uu.y)
                  + vvv.z * ftanh(vav.z + uu.z) + vvv.w * ftanh(vav.w + uu.w);
            }
#pragma unroll
            for (int off = 32; off; off >>= 1) p += __shfl_down(p, off);
            if (lane == 0) es_own[m] = p;
        }
        __syncthreads();
        if (tid < 96) ag_store(&esx[((size_t)b * 2 + half) * 96 + tid], es_own[tid]);
        set_flag(fB_own, t);
        wait_ge(fB_par, t);
        if (tid < 96) {
            float e = kNEG;
            if (rowm[tid] >= 0)
                e = es_own[tid] + ag_load(&esx[((size_t)b * 2 + (half ^ 1)) * 96 + tid]);
            es_sh[tid] = e;
        }
        __syncthreads();

        // ---- softmax over 96 (redundant in both halves, bitwise identical)
        if (tid < 64) {
            float a = es_sh[tid];
            float c = (tid < 32) ? es_sh[64 + tid] : kNEG;
            float mx = fmaxf(a, c);
#pragma unroll
            for (int off = 32; off; off >>= 1) mx = fmaxf(mx, __shfl_xor(mx, off));
            if (tid == 0) red0 = mx;
        }
        __syncthreads();
        if (tid < 96) w_sh[tid] = __expf(es_sh[tid] - red0);
        __syncthreads();
        if (tid < 64) {
            float a = w_sh[tid] + ((tid < 32) ? w_sh[64 + tid] : 0.0f);
#pragma unroll
            for (int off = 32; off; off >>= 1) a += __shfl_xor(a, off);
            if (tid == 0) red1 = 1.0f / a;
        }
        __syncthreads();

        // ---- ct over own cols (8-way row split), st half
        {
            float4 acc = {0, 0, 0, 0};
#pragma unroll
            for (int r = 0; r < 12; ++r) {
                int m = kq + 8 * r;
                int row = rowm[m];
                if (row >= 0) {
                    float wgt = w_sh[m];
                    const float4 hv = *reinterpret_cast<const float4*>(&hs[((size_t)row * kB + b) * kH + C0 + c4]);
                    acc.x += wgt * hv.x; acc.y += wgt * hv.y;
                    acc.z += wgt * hv.z; acc.w += wgt * hv.w;
                }
            }
            *reinterpret_cast<float4*>(&part[kq][c4]) = acc;
        }
        __syncthreads();
        if (tid < 256) {
            float ct = 0.0f;
#pragma unroll
            for (int j = 0; j < 8; ++j) ct += part[j][tid];
            float stv = 0.5f * (h_sh[C0 + tid] + ct * red1);
            sthalf[tid] = stv;
            ag_store(&stx[(size_t)b * kH + C0 + tid], stv);
        }
        set_flag(fS_own, t);

        // ---- long_scores accumulation + eviction (overlap partner's spin)
        if (tid < kK) {
            int row = rowm[tid];
            if (row >= 0) lsc_sh[row] += w_sh[tid] * red1;
        }
        __syncthreads();
        if (tid == 0 && t >= kK) {
            float score = lsc_sh[t - kK];
            int fc = fcnt_sh;
            bool nf = fc < kR;
            float mn = buck_sh[0]; int mp = 0;
            for (int r = 1; r < kR; ++r) {
                float bv = buck_sh[r];
                if (bv < mn) { mn = bv; mp = r; }
            }
            if (nf || score > mn) {
                int pos = nf ? fc : mp;
                lidx_sh[pos] = t - kK;
                buck_sh[pos] = score;
                if (nf) fcnt_sh = fc + 1;
            }
        }
        wait_ge(fS_par, t);
        // assemble full st: own half from LDS, partner half agent-coherent
        if ((tid >> 8) == half) st_sh[tid] = sthalf[tid & 255];
        else                    st_sh[tid] = ag_load(&stx[(size_t)b * kH + tid]);
        __syncthreads();

        // ---- matvec B (fused): h_pre[C] = st@Vw[:,C] + XU[t], va'[C] = st@Vaw[:,C]
        {
            float4 aw = {0, 0, 0, 0}, av = {0, 0, 0, 0};
#pragma unroll 4
            for (int k = 0; k < kH; k += 8) {
                float s = st_sh[k + kq];
                const float4 w1 = *reinterpret_cast<const float4*>(&Vw[(size_t)(k + kq) * kH + C0 + c4]);
                const float4 w2 = *reinterpret_cast<const float4*>(&Vaw[(size_t)(k + kq) * kH + C0 + c4]);
                aw.x += s * w1.x; aw.y += s * w1.y; aw.z += s * w1.z; aw.w += s * w1.w;
                av.x += s * w2.x; av.y += s * w2.y; av.z += s * w2.z; av.w += s * w2.w;
            }
            *reinterpret_cast<float4*>(&part[kq][c4]) = aw;
            *reinterpret_cast<float4*>(&part2[kq][c4]) = av;
        }
        __syncthreads();
        if (tid < 256) {
            float hpre = 0.0f, vnew = 0.0f;
#pragma unroll
            for (int j = 0; j < 8; ++j) { hpre += part[j][tid]; vnew += part2[j][tid]; }
            hpre += XU[((size_t)t * kB + b) * kH + C0 + tid];
            float hv = tanhf(hpre);
            va_sh[tid] = vnew;
            ag_store(&hs[((size_t)t * kB + b) * kH + C0 + tid], hv);
        }
        set_flag(fC_own, t + 1);
    }
}

// ---------------------------------------------------------------------------
extern "C" void kernel_launch(void* const* d_in, const int* in_sizes, int n_in,
                              void* d_out, int out_size, void* d_ws, size_t ws_size,
                              hipStream_t stream)
{
    const float* x   = (const float*)d_in[0];
    const float* Uw  = (const float*)d_in[1];
    const float* Ub  = (const float*)d_in[2];
    const float* Vw  = (const float*)d_in[3];
    const float* Uaw = (const float*)d_in[4];
    const float* Vaw = (const float*)d_in[5];
    const float* vv  = (const float*)d_in[6];
    float* hs = (float*)d_out;

    float* ws = (float*)d_ws;
    const size_t TBH = (size_t)kT * kB * kH;
    float* XU  = ws;                       // T*B*H
    float* HSU = XU + TBH;                 // T*B*H
    float* esx = HSU + TBH;                // B*2*96
    float* stx = esx + (size_t)kB * 2 * 96;   // B*H
    int*   flags = (int*)(stx + (size_t)kB * kH);  // B*3*2

    init_flags_k<<<3, 256, 0, stream>>>(flags);

    // XU = x @ Uw + Ub
    gemm_xu<<<dim3(kH / 64, (kT * kB) / 32), 256, 0, stream>>>(
        x, Uw, Ub, XU, kT * kB, kH, kINP);

    // pair-split recurrence: 2 blocks per batch element, 1 block per CU
    rnn_pair<<<2 * kB, 512, 0, stream>>>(Vw, Vaw, Uaw, vv, XU, HSU, hs, esx, stx, flags);
}

// Round 4
// 8832.413 us; speedup vs baseline: 3.1116x; 1.5497x over previous
//
#include <hip/hip_runtime.h>
#include <hip/hip_bf16.h>
#include <cstddef>

#define kT 256
#define kB 128
#define kINP 512
#define kH 512
#define kK 32
#define kR 64
#define kNEG (-1e30f)

// ---------------------------------------------------------------------------
// agent-scope (device-coherent, L1/L2-bypassing) accessors. RELAXED order:
// no cache invalidates/writebacks. Ordering between blocks is provided by
// the vmcnt(0) drain inside __syncthreads() before each flag store, since
// all cross-block traffic meets at the device coherence point.
// ---------------------------------------------------------------------------
__device__ __forceinline__ void ag_store(float* p, float v) {
    __hip_atomic_store(p, v, __ATOMIC_RELAXED, __HIP_MEMORY_SCOPE_AGENT);
}
__device__ __forceinline__ float ag_load(const float* p) {
    return __hip_atomic_load(p, __ATOMIC_RELAXED, __HIP_MEMORY_SCOPE_AGENT);
}

// fast tanh for attention scores (error ~1e-7, stable at +-inf)
__device__ __forceinline__ float ftanh(float x)
{
    float e = __expf(2.0f * x);
    return 1.0f - 2.0f * __builtin_amdgcn_rcpf(e + 1.0f);
}

// ---------------------------------------------------------------------------
// XU = x @ Uw + Ub   (M = T*B = 32768, N = K = 512), fp32 LDS-tiled GEMM
// ---------------------------------------------------------------------------
__global__ __launch_bounds__(256) void gemm_xu(
    const float* __restrict__ A, const float* __restrict__ W,
    const float* __restrict__ bias, float* __restrict__ C,
    int M, int N, int K)
{
    __shared__ float As[32][36];
    __shared__ float Ws[32][68];
    const int tid = threadIdx.x;
    const int n0 = blockIdx.x * 64;
    const int m0 = blockIdx.y * 32;
    const int ty = tid >> 4, tx = tid & 15;
    const int arow = tid >> 3, ac4 = (tid & 7) << 2;
    const int wrow = tid >> 4, wc4 = (tid & 15) << 2;

    float acc[2][4] = {};

    for (int k0 = 0; k0 < K; k0 += 32) {
        float4 av = *reinterpret_cast<const float4*>(&A[(size_t)(m0 + arow) * K + k0 + ac4]);
        float4 w0 = *reinterpret_cast<const float4*>(&W[(size_t)(k0 + wrow) * N + n0 + wc4]);
        float4 w1 = *reinterpret_cast<const float4*>(&W[(size_t)(k0 + wrow + 16) * N + n0 + wc4]);
        *reinterpret_cast<float4*>(&As[arow][ac4]) = av;
        *reinterpret_cast<float4*>(&Ws[wrow][wc4]) = w0;
        *reinterpret_cast<float4*>(&Ws[wrow + 16][wc4]) = w1;
        __syncthreads();
#pragma unroll
        for (int kk = 0; kk < 32; ++kk) {
            float a0 = As[ty * 2 + 0][kk];
            float a1 = As[ty * 2 + 1][kk];
            float4 wv = *reinterpret_cast<float4*>(&Ws[kk][tx * 4]);
            acc[0][0] += a0 * wv.x; acc[0][1] += a0 * wv.y;
            acc[0][2] += a0 * wv.z; acc[0][3] += a0 * wv.w;
            acc[1][0] += a1 * wv.x; acc[1][1] += a1 * wv.y;
            acc[1][2] += a1 * wv.z; acc[1][3] += a1 * wv.w;
        }
        __syncthreads();
    }

#pragma unroll
    for (int r = 0; r < 2; ++r) {
        int m = m0 + ty * 2 + r;
#pragma unroll
        for (int j = 0; j < 4; ++j) {
            int n = n0 + tx * 4 + j;
            C[(size_t)m * N + n] = acc[r][j] + bias[n];
        }
    }
}

__global__ __launch_bounds__(256) void init_flags_k(int* __restrict__ flags)
{
    int i = blockIdx.x * 256 + threadIdx.x;
    if (i < kB * 3 * 2) flags[i] = 0;
}

// ---------------------------------------------------------------------------
// Pair-split persistent recurrence: blockIdx = 2*b + half, 1024 threads.
// Column split: each block owns cols [half*256, half*256+256).
// Weight matvecs split into own-k / partner-k phases so the own-k half
// issues before the partner flag wait.
// ---------------------------------------------------------------------------
__global__ __launch_bounds__(1024) void rnn_pair(
    const float* __restrict__ Vw, const float* __restrict__ Vaw,
    const float* __restrict__ Uaw, const float* __restrict__ vvec,
    const float* __restrict__ XU, float* __restrict__ HSU,
    float* __restrict__ hs, float* __restrict__ esx,
    float* __restrict__ stx, int* __restrict__ flags)
{
    const int bid = blockIdx.x;
    const int b = bid >> 1, half = bid & 1;
    const int C0 = half << 8;            // own column base
    const int P0 = (half ^ 1) << 8;      // partner column base
    const int tid = threadIdx.x;
    const int kq = tid >> 6;             // 0..15 k-split group
    const int lane = tid & 63;
    const int c4 = lane << 2;            // float4 col offset within half

    __shared__ __align__(16) float h_sh[512];     // full h_{t-1}
    __shared__ __align__(16) float st_sh[512];    // full st
    __shared__ __align__(16) float va_sh[256];    // own cols of va
    __shared__ __align__(16) float u_sh[256];     // own cols of HSU[t-1]
    __shared__ __align__(16) float v_sh[256];     // own cols of v
    __shared__ __align__(16) float part[16][260];
    __shared__ __align__(16) float part2[16][260];
    __shared__ float es_own[96], es_sh[96], w_sh[96];
    __shared__ int   rowm[96];
    __shared__ float lsc_sh[kT];
    __shared__ float buck_sh[kR];
    __shared__ int   lidx_sh[kR];
    __shared__ int   fcnt_sh;
    __shared__ float red0, red1;

    int* fC_own = &flags[(b * 3 + 0) * 2 + half];
    int* fB_own = &flags[(b * 3 + 1) * 2 + half];
    int* fS_own = &flags[(b * 3 + 2) * 2 + half];
    int* fC_par = &flags[(b * 3 + 0) * 2 + (half ^ 1)];
    int* fB_par = &flags[(b * 3 + 1) * 2 + (half ^ 1)];
    int* fS_par = &flags[(b * 3 + 2) * 2 + (half ^ 1)];

    auto wait_ge = [&](int* f, int target) {
        if (tid == 0) {
            while (__hip_atomic_load(f, __ATOMIC_RELAXED, __HIP_MEMORY_SCOPE_AGENT) < target)
                __builtin_amdgcn_s_sleep(1);
        }
        __syncthreads();
    };
    auto set_flag = [&](int* f, int val) {
        __syncthreads();   // drains vmcnt(0): prior agent stores are at coherence point
        if (tid == 0)
            __hip_atomic_store(f, val, __ATOMIC_RELAXED, __HIP_MEMORY_SCOPE_AGENT);
    };

    // ---- prologue (t = 0)
    if (tid < 256) { v_sh[tid] = vvec[C0 + tid]; lsc_sh[tid] = 0.0f; }
    if (tid < kR) { buck_sh[tid] = 0.0f; lidx_sh[tid] = -1; }
    if (tid == 0) fcnt_sh = 0;
    if (tid < 512) st_sh[tid] = XU[(size_t)b * kH + tid];   // st_0 = pre
    __syncthreads();
    if (tid < 256) {
        float h0 = tanhf(st_sh[C0 + tid]);
        h_sh[C0 + tid] = h0;
        ag_store(&hs[(size_t)b * kH + C0 + tid], h0);
    }
    set_flag(fC_own, 1);
    // va_0 = st_0 @ Vaw[:, C]  (full k, no partner needed: st_0 from XU)
    {
        float4 acc = {0, 0, 0, 0};
#pragma unroll 8
        for (int k = kq; k < kH; k += 16) {
            float s = st_sh[k];
            const float4 w = *reinterpret_cast<const float4*>(&Vaw[(size_t)k * kH + C0 + c4]);
            acc.x += s * w.x; acc.y += s * w.y; acc.z += s * w.z; acc.w += s * w.w;
        }
        *reinterpret_cast<float4*>(&part[kq][c4]) = acc;
        __syncthreads();
        if (tid < 256) {
            float s = 0.0f;
#pragma unroll
            for (int j = 0; j < 16; ++j) s += part[j][tid];
            va_sh[tid] = s;
        }
        __syncthreads();
    }

    for (int t = 1; t < kT; ++t) {
        // XU[t] prefetch for the epilogue (plain cached load, issued early)
        float xu_reg = 0.0f;
        if (tid < 256) xu_reg = XU[((size_t)t * kB + b) * kH + C0 + tid];

        // ---- matvec A phase 1: own-k half of u = h_{t-1} @ Uaw[:, C]
        float4 accA = {0, 0, 0, 0};
#pragma unroll 8
        for (int k = C0 + kq; k < C0 + 256; k += 16) {
            float s = h_sh[k];
            const float4 w = *reinterpret_cast<const float4*>(&Uaw[(size_t)k * kH + C0 + c4]);
            accA.x += s * w.x; accA.y += s * w.y; accA.z += s * w.z; accA.w += s * w.w;
        }
        if (tid < 96) {
            int row;
            if (tid < kK) { int md = (t + 31 - tid) & 31; row = t - 1 - md; }
            else row = lidx_sh[tid - kK];
            rowm[tid] = row;
        }
        // ---- wait for partner h_{t-1} half; fetch it
        wait_ge(fC_par, t);
        if (tid < 256) h_sh[P0 + tid] = ag_load(&hs[((size_t)(t - 1) * kB + b) * kH + P0 + tid]);
        __syncthreads();
        // ---- matvec A phase 2: partner-k half
#pragma unroll 8
        for (int k = P0 + kq; k < P0 + 256; k += 16) {
            float s = h_sh[k];
            const float4 w = *reinterpret_cast<const float4*>(&Uaw[(size_t)k * kH + C0 + c4]);
            accA.x += s * w.x; accA.y += s * w.y; accA.z += s * w.z; accA.w += s * w.w;
        }
        *reinterpret_cast<float4*>(&part[kq][c4]) = accA;
        __syncthreads();
        if (tid < 256) {
            float u = 0.0f;
#pragma unroll
            for (int j = 0; j < 16; ++j) u += part[j][tid];
            u_sh[tid] = u;
            HSU[((size_t)(t - 1) * kB + b) * kH + C0 + tid] = u;  // block-private
        }
        __syncthreads();

        // ---- es column-partials over own 256 cols (96 rows, 6/wave)
#pragma unroll
        for (int r = 0; r < 6; ++r) {
            int m = kq * 6 + r;
            int row = rowm[m];
            float p = 0.0f;
            if (row >= 0) {
                float4 uu;
                if (row == t - 1) uu = *reinterpret_cast<const float4*>(&u_sh[c4]);
                else uu = *reinterpret_cast<const float4*>(&HSU[((size_t)row * kB + b) * kH + C0 + c4]);
                const float4 vav = *reinterpret_cast<const float4*>(&va_sh[c4]);
                const float4 vvv = *reinterpret_cast<const float4*>(&v_sh[c4]);
                p = vvv.x * ftanh(vav.x + uu.x) + vvv.y * ftanh(vav.y + uu.y)
                  + vvv.z * ftanh(vav.z + uu.z) + vvv.w * ftanh(vav.w + uu.w);
            }
#pragma unroll
            for (int off = 32; off; off >>= 1) p += __shfl_down(p, off);
            if (lane == 0) es_own[m] = p;
        }
        __syncthreads();
        if (tid < 96) ag_store(&esx[((size_t)b * 2 + half) * 96 + tid], es_own[tid]);
        set_flag(fB_own, t);
        wait_ge(fB_par, t);
        if (tid < 96) {
            float e = kNEG;
            if (rowm[tid] >= 0)
                e = es_own[tid] + ag_load(&esx[((size_t)b * 2 + (half ^ 1)) * 96 + tid]);
            es_sh[tid] = e;
        }
        __syncthreads();

        // ---- softmax over 96 (redundant in both halves, bitwise identical)
        if (tid < 64) {
            float a = es_sh[tid];
            float c = (tid < 32) ? es_sh[64 + tid] : kNEG;
            float mx = fmaxf(a, c);
#pragma unroll
            for (int off = 32; off; off >>= 1) mx = fmaxf(mx, __shfl_xor(mx, off));
            if (tid == 0) red0 = mx;
        }
        __syncthreads();
        if (tid < 96) w_sh[tid] = __expf(es_sh[tid] - red0);
        __syncthreads();
        if (tid < 64) {
            float a = w_sh[tid] + ((tid < 32) ? w_sh[64 + tid] : 0.0f);
#pragma unroll
            for (int off = 32; off; off >>= 1) a += __shfl_xor(a, off);
            if (tid == 0) red1 = 1.0f / a;
        }
        __syncthreads();

        // ---- ct over own cols (16-way row split), st own half
        {
            float4 acc = {0, 0, 0, 0};
#pragma unroll
            for (int r = 0; r < 6; ++r) {
                int m = kq + (r << 4);
                int row = rowm[m];
                if (row >= 0) {
                    float wgt = w_sh[m];
                    float4 hv;
                    if (row == t - 1) hv = *reinterpret_cast<const float4*>(&h_sh[C0 + c4]);
                    else hv = *reinterpret_cast<const float4*>(&hs[((size_t)row * kB + b) * kH + C0 + c4]);
                    acc.x += wgt * hv.x; acc.y += wgt * hv.y;
                    acc.z += wgt * hv.z; acc.w += wgt * hv.w;
                }
            }
            *reinterpret_cast<float4*>(&part[kq][c4]) = acc;
        }
        __syncthreads();
        if (tid < 256) {
            float ct = 0.0f;
#pragma unroll
            for (int j = 0; j < 16; ++j) ct += part[j][tid];
            float stv = 0.5f * (h_sh[C0 + tid] + ct * red1);
            st_sh[C0 + tid] = stv;
            ag_store(&stx[(size_t)b * kH + C0 + tid], stv);
        }
        set_flag(fS_own, t);

        // ---- long_scores accumulation + eviction (overlaps partner skew)
        if (tid < kK) {
            int row = rowm[tid];
            if (row >= 0) lsc_sh[row] += w_sh[tid] * red1;
        }
        __syncthreads();
        if (tid == 0 && t >= kK) {
            float score = lsc_sh[t - kK];
            int fc = fcnt_sh;
            bool nf = fc < kR;
            float mn = buck_sh[0]; int mp = 0;
            for (int r = 1; r < kR; ++r) {
                float bv = buck_sh[r];
                if (bv < mn) { mn = bv; mp = r; }
            }
            if (nf || score > mn) {
                int pos = nf ? fc : mp;
                lidx_sh[pos] = t - kK;
                buck_sh[pos] = score;
                if (nf) fcnt_sh = fc + 1;
            }
        }

        // ---- matvec B phase 1 (own-k): [h_pre | va'] partial from own st half
        float4 aw = {0, 0, 0, 0}, av = {0, 0, 0, 0};
#pragma unroll 8
        for (int k = C0 + kq; k < C0 + 256; k += 16) {
            float s = st_sh[k];
            const float4 w1 = *reinterpret_cast<const float4*>(&Vw[(size_t)k * kH + C0 + c4]);
            const float4 w2 = *reinterpret_cast<const float4*>(&Vaw[(size_t)k * kH + C0 + c4]);
            aw.x += s * w1.x; aw.y += s * w1.y; aw.z += s * w1.z; aw.w += s * w1.w;
            av.x += s * w2.x; av.y += s * w2.y; av.z += s * w2.z; av.w += s * w2.w;
        }
        // ---- wait partner st half
        wait_ge(fS_par, t);
        if (tid < 256) st_sh[P0 + tid] = ag_load(&stx[(size_t)b * kH + P0 + tid]);
        __syncthreads();
        // ---- matvec B phase 2 (partner-k)
#pragma unroll 8
        for (int k = P0 + kq; k < P0 + 256; k += 16) {
            float s = st_sh[k];
            const float4 w1 = *reinterpret_cast<const float4*>(&Vw[(size_t)k * kH + C0 + c4]);
            const float4 w2 = *reinterpret_cast<const float4*>(&Vaw[(size_t)k * kH + C0 + c4]);
            aw.x += s * w1.x; aw.y += s * w1.y; aw.z += s * w1.z; aw.w += s * w1.w;
            av.x += s * w2.x; av.y += s * w2.y; av.z += s * w2.z; av.w += s * w2.w;
        }
        *reinterpret_cast<float4*>(&part[kq][c4]) = aw;
        *reinterpret_cast<float4*>(&part2[kq][c4]) = av;
        __syncthreads();
        if (tid < 256) {
            float hpre = xu_reg, vnew = 0.0f;
#pragma unroll
            for (int j = 0; j < 16; ++j) { hpre += part[j][tid]; vnew += part2[j][tid]; }
            float hv = tanhf(hpre);
            h_sh[C0 + tid] = hv;
            va_sh[tid] = vnew;
            ag_store(&hs[((size_t)t * kB + b) * kH + C0 + tid], hv);
        }
        set_flag(fC_own, t + 1);
    }
}

// ---------------------------------------------------------------------------
extern "C" void kernel_launch(void* const* d_in, const int* in_sizes, int n_in,
                              void* d_out, int out_size, void* d_ws, size_t ws_size,
                              hipStream_t stream)
{
    const float* x   = (const float*)d_in[0];
    const float* Uw  = (const float*)d_in[1];
    const float* Ub  = (const float*)d_in[2];
    const float* Vw  = (const float*)d_in[3];
    const float* Uaw = (const float*)d_in[4];
    const float* Vaw = (const float*)d_in[5];
    const float* vv  = (const float*)d_in[6];
    float* hs = (float*)d_out;

    float* ws = (float*)d_ws;
    const size_t TBH = (size_t)kT * kB * kH;
    float* XU  = ws;                       // T*B*H
    float* HSU = XU + TBH;                 // T*B*H
    float* esx = HSU + TBH;                // B*2*96
    float* stx = esx + (size_t)kB * 2 * 96;   // B*H
    int*   flags = (int*)(stx + (size_t)kB * kH);  // B*3*2

    init_flags_k<<<3, 256, 0, stream>>>(flags);

    // XU = x @ Uw + Ub
    gemm_xu<<<dim3(kH / 64, (kT * kB) / 32), 256, 0, stream>>>(
        x, Uw, Ub, XU, kT * kB, kH, kINP);

    // pair-split recurrence: 2 blocks per batch element, 1024 threads each
    rnn_pair<<<2 * kB, 1024, 0, stream>>>(Vw, Vaw, Uaw, vv, XU, HSU, hs, esx, stx, flags);
}

// Round 5
// 5629.711 us; speedup vs baseline: 4.8817x; 1.5689x over previous
//
#include <hip/hip_runtime.h>
#include <hip/hip_bf16.h>
#include <cstddef>

#define kT 256
#define kB 128
#define kINP 512
#define kH 512
#define kK 32
#define kR 64
#define kNEG (-1e30f)

// ---------------------------------------------------------------------------
// agent-scope (device-coherent, L1/L2-bypassing) accessors, RELAXED order.
// Ordering across the block pair comes from the vmcnt(0) drain inside
// __syncthreads() before each flag store (protocol validated in r3/r4).
// ---------------------------------------------------------------------------
__device__ __forceinline__ void ag_store(float* p, float v) {
    __hip_atomic_store(p, v, __ATOMIC_RELAXED, __HIP_MEMORY_SCOPE_AGENT);
}
__device__ __forceinline__ float ag_load(const float* p) {
    return __hip_atomic_load(p, __ATOMIC_RELAXED, __HIP_MEMORY_SCOPE_AGENT);
}

// fast tanh for attention scores (error ~1e-7, stable at +-inf)
__device__ __forceinline__ float ftanh(float x)
{
    float e = __expf(2.0f * x);
    return 1.0f - 2.0f * __builtin_amdgcn_rcpf(e + 1.0f);
}

// ---------------------------------------------------------------------------
// XU = x @ Uw + Ub   (M = T*B = 32768, N = K = 512), fp32 LDS-tiled GEMM
// ---------------------------------------------------------------------------
__global__ __launch_bounds__(256) void gemm_xu(
    const float* __restrict__ A, const float* __restrict__ W,
    const float* __restrict__ bias, float* __restrict__ C,
    int M, int N, int K)
{
    __shared__ float As[32][36];
    __shared__ float Ws[32][68];
    const int tid = threadIdx.x;
    const int n0 = blockIdx.x * 64;
    const int m0 = blockIdx.y * 32;
    const int ty = tid >> 4, tx = tid & 15;
    const int arow = tid >> 3, ac4 = (tid & 7) << 2;
    const int wrow = tid >> 4, wc4 = (tid & 15) << 2;

    float acc[2][4] = {};

    for (int k0 = 0; k0 < K; k0 += 32) {
        float4 av = *reinterpret_cast<const float4*>(&A[(size_t)(m0 + arow) * K + k0 + ac4]);
        float4 w0 = *reinterpret_cast<const float4*>(&W[(size_t)(k0 + wrow) * N + n0 + wc4]);
        float4 w1 = *reinterpret_cast<const float4*>(&W[(size_t)(k0 + wrow + 16) * N + n0 + wc4]);
        *reinterpret_cast<float4*>(&As[arow][ac4]) = av;
        *reinterpret_cast<float4*>(&Ws[wrow][wc4]) = w0;
        *reinterpret_cast<float4*>(&Ws[wrow + 16][wc4]) = w1;
        __syncthreads();
#pragma unroll
        for (int kk = 0; kk < 32; ++kk) {
            float a0 = As[ty * 2 + 0][kk];
            float a1 = As[ty * 2 + 1][kk];
            float4 wv = *reinterpret_cast<float4*>(&Ws[kk][tx * 4]);
            acc[0][0] += a0 * wv.x; acc[0][1] += a0 * wv.y;
            acc[0][2] += a0 * wv.z; acc[0][3] += a0 * wv.w;
            acc[1][0] += a1 * wv.x; acc[1][1] += a1 * wv.y;
            acc[1][2] += a1 * wv.z; acc[1][3] += a1 * wv.w;
        }
        __syncthreads();
    }

#pragma unroll
    for (int r = 0; r < 2; ++r) {
        int m = m0 + ty * 2 + r;
#pragma unroll
        for (int j = 0; j < 4; ++j) {
            int n = n0 + tx * 4 + j;
            C[(size_t)m * N + n] = acc[r][j] + bias[n];
        }
    }
}

__global__ __launch_bounds__(256) void init_flags_k(int* __restrict__ flags)
{
    int i = blockIdx.x * 256 + threadIdx.x;
    if (i < kB * 3 * 2) flags[i] = 0;
}

// ---------------------------------------------------------------------------
// Pair-split persistent recurrence: blockIdx = 2*b + half, 1024 threads.
// All attention-memory rows (own 256-col half) cached on-chip:
//   shortH/shortU: last-32 h / h@Uaw rows, fp32 LDS circular buffers
//   longH: 64-slot long-term h rows, fp32 LDS (position-indexed)
//   lngU:  64-slot long-term u rows, block-private compact global (L2-resident)
// Weight matvecs split own-k / partner-k around the pair flag waits.
// ---------------------------------------------------------------------------
__global__ __launch_bounds__(1024) void rnn_pair(
    const float* __restrict__ Vw, const float* __restrict__ Vaw,
    const float* __restrict__ Uaw, const float* __restrict__ vvec,
    const float* __restrict__ XU, float* __restrict__ lngU,
    float* __restrict__ hs, float* __restrict__ esx,
    float* __restrict__ stx, int* __restrict__ flags)
{
    extern __shared__ float dyn[];
    float* shortH = dyn;               // [32][256]
    float* shortU = dyn + 32 * 256;    // [32][256]
    float* longH  = dyn + 64 * 256;    // [64][256]
    float* part   = dyn + 128 * 256;   // [16][264]
    const int PSTR = 264;

    const int bid = blockIdx.x;
    const int b = bid >> 1, half = bid & 1;
    const int C0 = half << 8;            // own column base
    const int P0 = (half ^ 1) << 8;      // partner column base
    const int tid = threadIdx.x;
    const int kq = tid >> 6;             // 0..15 (wave id / k-split group)
    const int lane = tid & 63;
    const int c4 = lane << 2;            // float4 col offset within half

    __shared__ __align__(16) float h_sh[512];     // full h_{t-1}
    __shared__ __align__(16) float st_sh[512];    // full st
    __shared__ __align__(16) float va_sh[256];    // own cols of va
    __shared__ __align__(16) float v_sh[256];     // own cols of v
    __shared__ float es_own[96], es_sh[96], w_sh[96];
    __shared__ int   rowm[96];
    __shared__ float lsc_sh[kT];
    __shared__ float buck_sh[kR];
    __shared__ int   lidx_sh[kR];
    __shared__ int   fcnt_sh, evict_pos;
    __shared__ float red0, red1;

    float* lngU_b = lngU + (size_t)bid * kR * 256;

    int* fC_own = &flags[(b * 3 + 0) * 2 + half];
    int* fB_own = &flags[(b * 3 + 1) * 2 + half];
    int* fS_own = &flags[(b * 3 + 2) * 2 + half];
    int* fC_par = &flags[(b * 3 + 0) * 2 + (half ^ 1)];
    int* fB_par = &flags[(b * 3 + 1) * 2 + (half ^ 1)];
    int* fS_par = &flags[(b * 3 + 2) * 2 + (half ^ 1)];

    auto wait_ge = [&](int* f, int target) {
        if (tid == 0) {
            while (__hip_atomic_load(f, __ATOMIC_RELAXED, __HIP_MEMORY_SCOPE_AGENT) < target)
                __builtin_amdgcn_s_sleep(1);
        }
        __syncthreads();
    };
    auto set_flag = [&](int* f, int val) {
        __syncthreads();   // drains vmcnt(0): prior agent stores at coherence point
        if (tid == 0)
            __hip_atomic_store(f, val, __ATOMIC_RELAXED, __HIP_MEMORY_SCOPE_AGENT);
    };

    // ---- prologue (t = 0)
    if (tid < 256) { v_sh[tid] = vvec[C0 + tid]; lsc_sh[tid] = 0.0f; }
    if (tid < kR) { buck_sh[tid] = 0.0f; lidx_sh[tid] = -1; }
    if (tid == 0) fcnt_sh = 0;
    if (tid < 512) st_sh[tid] = XU[(size_t)b * kH + tid];   // st_0 = pre
    __syncthreads();
    if (tid < 256) {
        float h0 = tanhf(st_sh[C0 + tid]);
        h_sh[C0 + tid] = h0;
        shortH[tid] = h0;                       // slot 0 = h_0
        ag_store(&hs[(size_t)b * kH + C0 + tid], h0);
    }
    set_flag(fC_own, 1);
    // va_0 = st_0 @ Vaw[:, C]  (full k: st_0 known from XU, no partner needed)
    {
        float4 acc = {0, 0, 0, 0};
#pragma unroll 8
        for (int k = kq; k < kH; k += 16) {
            float s = st_sh[k];
            const float4 w = *reinterpret_cast<const float4*>(&Vaw[(size_t)k * kH + C0 + c4]);
            acc.x += s * w.x; acc.y += s * w.y; acc.z += s * w.z; acc.w += s * w.w;
        }
        *reinterpret_cast<float4*>(&part[kq * PSTR + c4]) = acc;
        __syncthreads();
        if (tid < 256) {
            float s = 0.0f;
#pragma unroll
            for (int j = 0; j < 16; ++j) s += part[j * PSTR + tid];
            va_sh[tid] = s;
        }
        __syncthreads();
    }

    for (int t = 1; t < kT; ++t) {
        // XU[t] prefetch for the matvec-B epilogue
        float xu_reg = 0.0f;
        if (tid < 256) xu_reg = XU[((size_t)t * kB + b) * kH + C0 + tid];

        // ---- matvec A phase 1 (own-k): u = h_{t-1} @ Uaw[:, C]
        float4 accA = {0, 0, 0, 0};
#pragma unroll 8
        for (int k = C0 + kq; k < C0 + 256; k += 16) {
            float s = h_sh[k];
            const float4 w = *reinterpret_cast<const float4*>(&Uaw[(size_t)k * kH + C0 + c4]);
            accA.x += s * w.x; accA.y += s * w.y; accA.z += s * w.z; accA.w += s * w.w;
        }
        if (tid < 96) {
            int row;
            if (tid < kK) { int md = (t + 31 - tid) & 31; row = t - 1 - md; }
            else row = lidx_sh[tid - kK];     // >=0 means slot filled
            rowm[tid] = row;
        }
        wait_ge(fC_par, t);
        if (tid < 256) h_sh[P0 + tid] = ag_load(&hs[((size_t)(t - 1) * kB + b) * kH + P0 + tid]);
        __syncthreads();
        // ---- matvec A phase 2 (partner-k)
#pragma unroll 8
        for (int k = P0 + kq; k < P0 + 256; k += 16) {
            float s = h_sh[k];
            const float4 w = *reinterpret_cast<const float4*>(&Uaw[(size_t)k * kH + C0 + c4]);
            accA.x += s * w.x; accA.y += s * w.y; accA.z += s * w.z; accA.w += s * w.w;
        }
        *reinterpret_cast<float4*>(&part[kq * PSTR + c4]) = accA;
        __syncthreads();
        if (tid < 256) {
            float u = 0.0f;
#pragma unroll
            for (int j = 0; j < 16; ++j) u += part[j * PSTR + tid];
            shortU[((t - 1) & 31) * 256 + tid] = u;     // slot (t-1)%32
        }
        __syncthreads();

        // ---- es partials over own cols: wave kq handles rows m = kq + 16r
        {
            float4 uu[6];
            int rv[6];
#pragma unroll
            for (int r = 0; r < 6; ++r) {
                int m = kq + (r << 4);
                int row = rowm[m];
                rv[r] = row;
                uu[r] = make_float4(0.f, 0.f, 0.f, 0.f);
                if (row >= 0) {
                    const float* up = (m < kK) ? &shortU[m * 256]
                                               : &lngU_b[(size_t)(m - kK) * 256];
                    uu[r] = *reinterpret_cast<const float4*>(&up[c4]);
                }
            }
            const float4 vav = *reinterpret_cast<const float4*>(&va_sh[c4]);
            const float4 vvv = *reinterpret_cast<const float4*>(&v_sh[c4]);
#pragma unroll
            for (int r = 0; r < 6; ++r) {
                float p = 0.0f;
                if (rv[r] >= 0) {
                    p = vvv.x * ftanh(vav.x + uu[r].x) + vvv.y * ftanh(vav.y + uu[r].y)
                      + vvv.z * ftanh(vav.z + uu[r].z) + vvv.w * ftanh(vav.w + uu[r].w);
                }
#pragma unroll
                for (int off = 32; off; off >>= 1) p += __shfl_down(p, off);
                if (lane == 0) es_own[kq + (r << 4)] = p;
            }
        }
        __syncthreads();
        if (tid < 96) ag_store(&esx[((size_t)b * 2 + half) * 96 + tid], es_own[tid]);
        set_flag(fB_own, t);
        wait_ge(fB_par, t);
        if (tid < 96) {
            float e = kNEG;
            if (rowm[tid] >= 0)
                e = es_own[tid] + ag_load(&esx[((size_t)b * 2 + (half ^ 1)) * 96 + tid]);
            es_sh[tid] = e;
        }
        __syncthreads();

        // ---- softmax over 96 (redundant in both halves, bitwise identical)
        if (tid < 64) {
            float a = es_sh[tid];
            float c = (tid < 32) ? es_sh[64 + tid] : kNEG;
            float mx = fmaxf(a, c);
#pragma unroll
            for (int off = 32; off; off >>= 1) mx = fmaxf(mx, __shfl_xor(mx, off));
            if (tid == 0) red0 = mx;
        }
        __syncthreads();
        if (tid < 96) w_sh[tid] = __expf(es_sh[tid] - red0);
        __syncthreads();
        if (tid < 64) {
            float a = w_sh[tid] + ((tid < 32) ? w_sh[64 + tid] : 0.0f);
#pragma unroll
            for (int off = 32; off; off >>= 1) a += __shfl_xor(a, off);
            if (tid == 0) red1 = 1.0f / a;
        }
        __syncthreads();

        // ---- ct over own cols: all rows from LDS (shortH / longH)
        {
            float4 acc = {0, 0, 0, 0};
#pragma unroll
            for (int r = 0; r < 6; ++r) {
                int m = kq + (r << 4);
                int row = rowm[m];
                if (row >= 0) {
                    const float* hp = (m < kK) ? &shortH[m * 256]
                                               : &longH[(m - kK) * 256];
                    const float4 hv = *reinterpret_cast<const float4*>(&hp[c4]);
                    float wgt = w_sh[m];
                    acc.x += wgt * hv.x; acc.y += wgt * hv.y;
                    acc.z += wgt * hv.z; acc.w += wgt * hv.w;
                }
            }
            *reinterpret_cast<float4*>(&part[kq * PSTR + c4]) = acc;
        }
        __syncthreads();
        if (tid < 256) {
            float ct = 0.0f;
#pragma unroll
            for (int j = 0; j < 16; ++j) ct += part[j * PSTR + tid];
            float stv = 0.5f * (h_sh[C0 + tid] + ct * red1);
            st_sh[C0 + tid] = stv;
            ag_store(&stx[(size_t)b * kH + C0 + tid], stv);
        }
        set_flag(fS_own, t);

        // ---- long_scores accumulation, then eviction decision (ref order)
        if (tid < kK) {
            int row = rowm[tid];
            if (row >= 0) lsc_sh[row] += w_sh[tid] * red1;
        }
        __syncthreads();
        if (tid == 0) {
            int ep = -1;
            if (t >= kK) {
                float score = lsc_sh[t - kK];
                int fc = fcnt_sh;
                bool nf = fc < kR;
                float mn = buck_sh[0]; int mp = 0;
                for (int r = 1; r < kR; ++r) {
                    float bv = buck_sh[r];
                    if (bv < mn) { mn = bv; mp = r; }
                }
                if (nf || score > mn) {
                    ep = nf ? fc : mp;
                    lidx_sh[ep] = t - kK;
                    buck_sh[ep] = score;
                    if (nf) fcnt_sh = fc + 1;
                }
            }
            evict_pos = ep;
        }
        __syncthreads();
        // evicted candidate = h_{t-32} = shortH slot t%32 (u likewise) —
        // copy BEFORE the slot is overwritten with h_t at step end.
        if (evict_pos >= 0 && tid < 256) {
            longH[evict_pos * 256 + tid] = shortH[(t & 31) * 256 + tid];
            lngU_b[(size_t)evict_pos * 256 + tid] = shortU[(t & 31) * 256 + tid];
        }

        // ---- matvec B pass 1 (Vw): h_pre[C] = st @ Vw[:, C] + XU[t]
        {
            float4 aw = {0, 0, 0, 0};
#pragma unroll 8
            for (int k = C0 + kq; k < C0 + 256; k += 16) {
                float s = st_sh[k];
                const float4 w = *reinterpret_cast<const float4*>(&Vw[(size_t)k * kH + C0 + c4]);
                aw.x += s * w.x; aw.y += s * w.y; aw.z += s * w.z; aw.w += s * w.w;
            }
            wait_ge(fS_par, t);
            if (tid < 256) st_sh[P0 + tid] = ag_load(&stx[(size_t)b * kH + P0 + tid]);
            __syncthreads();
#pragma unroll 8
            for (int k = P0 + kq; k < P0 + 256; k += 16) {
                float s = st_sh[k];
                const float4 w = *reinterpret_cast<const float4*>(&Vw[(size_t)k * kH + C0 + c4]);
                aw.x += s * w.x; aw.y += s * w.y; aw.z += s * w.z; aw.w += s * w.w;
            }
            *reinterpret_cast<float4*>(&part[kq * PSTR + c4]) = aw;
        }
        __syncthreads();
        if (tid < 256) {
            float hpre = xu_reg;
#pragma unroll
            for (int j = 0; j < 16; ++j) hpre += part[j * PSTR + tid];
            float hv = tanhf(hpre);
            h_sh[C0 + tid] = hv;
            shortH[(t & 31) * 256 + tid] = hv;      // slot t%32 <- h_t
            ag_store(&hs[((size_t)t * kB + b) * kH + C0 + tid], hv);
        }
        set_flag(fC_own, t + 1);   // unblock partner's next matvec-A early

        // ---- matvec B pass 2 (Vaw): va'[C] = st @ Vaw[:, C]  (full k)
        {
            float4 av = {0, 0, 0, 0};
#pragma unroll 8
            for (int k = kq; k < kH; k += 16) {
                float s = st_sh[k];
                const float4 w = *reinterpret_cast<const float4*>(&Vaw[(size_t)k * kH + C0 + c4]);
                av.x += s * w.x; av.y += s * w.y; av.z += s * w.z; av.w += s * w.w;
            }
            *reinterpret_cast<float4*>(&part[kq * PSTR + c4]) = av;
        }
        __syncthreads();
        if (tid < 256) {
            float vn = 0.0f;
#pragma unroll
            for (int j = 0; j < 16; ++j) vn += part[j * PSTR + tid];
            va_sh[tid] = vn;
        }
        __syncthreads();
    }
}

// ---------------------------------------------------------------------------
extern "C" void kernel_launch(void* const* d_in, const int* in_sizes, int n_in,
                              void* d_out, int out_size, void* d_ws, size_t ws_size,
                              hipStream_t stream)
{
    const float* x   = (const float*)d_in[0];
    const float* Uw  = (const float*)d_in[1];
    const float* Ub  = (const float*)d_in[2];
    const float* Vw  = (const float*)d_in[3];
    const float* Uaw = (const float*)d_in[4];
    const float* Vaw = (const float*)d_in[5];
    const float* vv  = (const float*)d_in[6];
    float* hs = (float*)d_out;

    float* ws = (float*)d_ws;
    const size_t TBH = (size_t)kT * kB * kH;
    float* XU   = ws;                            // T*B*H
    float* lngU = XU + TBH;                      // 2*B * 64 * 256
    float* esx  = lngU + (size_t)2 * kB * kR * 256;
    float* stx  = esx + (size_t)kB * 2 * 96;     // B*H
    int*   flags = (int*)(stx + (size_t)kB * kH);  // B*3*2

    // dynamic LDS: shortH(32K) + shortU(32K) + longH(64K) + part(16.5K)
    const int dyn_bytes = (32 * 256 + 32 * 256 + 64 * 256 + 16 * 264) * 4;
    static int lds_cfg = 0;
    if (!lds_cfg) {
        hipFuncSetAttribute(reinterpret_cast<const void*>(rnn_pair),
                            hipFuncAttributeMaxDynamicSharedMemorySize, dyn_bytes);
        lds_cfg = 1;
    }

    init_flags_k<<<3, 256, 0, stream>>>(flags);

    // XU = x @ Uw + Ub
    gemm_xu<<<dim3(kH / 64, (kT * kB) / 32), 256, 0, stream>>>(
        x, Uw, Ub, XU, kT * kB, kH, kINP);

    // pair-split recurrence: 2 blocks per batch element, 1024 threads each
    rnn_pair<<<2 * kB, 1024, dyn_bytes, stream>>>(
        Vw, Vaw, Uaw, vv, XU, lngU, hs, esx, stx, flags);
}